// Round 5
// baseline (534.858 us; speedup 1.0000x reference)
//
#include <hip/hip_runtime.h>
#include <math.h>

#define ALPHA 0.42f
#define H 1024
#define W 1024
#define NCH 48
#define BH 64
#define NBANDS (H / BH)     // 16 bands; grid (16,48) = 768 blocks -> 3/CU, one clean round

typedef float nfloat4 __attribute__((ext_vector_type(4)));

__device__ __forceinline__ float sigf(float x) {
    return __builtin_amdgcn_rcpf(1.0f + __expf(-x));
}

// LDS handoff barrier that does NOT drain vmcnt: keeps the global prefetch
// ring in flight across the barrier. lgkmcnt(0) retires this wave's ds ops.
__device__ __forceinline__ void block_sync_lds() {
    asm volatile("s_waitcnt lgkmcnt(0)" ::: "memory");
    __builtin_amdgcn_s_barrier();
    asm volatile("" ::: "memory");
}

// ---------------------------------------------------------------------------
// score walk, templated on EDGE:
//   EDGE=false (14/16 bands): all ingested rows in-range (no clamps, no
//   validity cndmasks) and all emitted rows have fy==7 (precomputed wf) —
//   ~13 fewer VALU/row.
//   EDGE=true (first/last band): general path with clamps + fy chain.
// Pair-stepping: 2 rows per barrier (35 barriers); 4-slot LDS row ring for
// the horizontal halo; depth-8 global prefetch ring (4 pairs ahead, ~1840
// device-cycles in flight > 900-cycle HBM latency).
// LDS race check: pair p writes lrow slots {n&3,(n+1)&3} pre-barrier, reads
// post-barrier; those reads retire at the lgkmcnt(0) of barrier p+1; the
// next write to the same slots is in pair p+2, after barrier p+1 -> safe.
// ---------------------------------------------------------------------------
template<bool EDGE>
__device__ __forceinline__ float score_walk(const float* __restrict__ gbase,
                                            float (*lrow)[1032],
                                            const int band, const int c4,
                                            const float wfxc0, const float wfxc1,
                                            const float wfxc2, const float wfxc3)
{
    float4 vb[8];                                    // global prefetch ring, depth 8
    float srm[8], sr0[8], sr1[8], sr2[8], sr3[8], srp[8];
    float rsA[8], rsB[8], rsC[8], rsD[8];
    float vs0 = 0.f, vs1 = 0.f, vs2 = 0.f, vs3 = 0.f, acc = 0.f;
    #pragma unroll
    for (int k = 0; k < 8; ++k) { rsA[k] = rsB[k] = rsC[k] = rsD[k] = 0.f; }

    const float wf70 = 7.f * wfxc0, wf71 = 7.f * wfxc1;
    const float wf72 = 7.f * wfxc2, wf73 = 7.f * wfxc3;

    auto LOADROW = [&](int g, int slot) {
        int gc = EDGE ? min(max(g, 0), H - 1) : g;   // interior: always in-range
        vb[slot] = *(const float4*)(gbase + ((size_t)gc << 10));
    };

    auto INGEST = [&](int m, float q0, float q1, float q2, float q3, int sl, bool doEmit) {
        const int s8 = m & 7;
        float4 hl = *(const float4*)&lrow[sl][c4];       // cols c4-4..c4-1
        float4 hr = *(const float4*)&lrow[sl][c4 + 8];   // cols c4+4..c4+7
        float l1 = hl.y, l2 = hl.z, l3 = hl.w;
        float r0 = hr.x, r1 = hr.y, r2 = hr.z;
        float a = ((l1 + l2) + (l3 + q0)) + ((q1 + q2) + q3);
        float b = a - l1 + r0;
        float c = b - l2 + r1;
        float d = c - l3 + r2;
        const int old = (s8 + 1) & 7;                // row m-7 leaves vertical window
        vs0 += a - rsA[old]; vs1 += b - rsB[old]; vs2 += c - rsC[old]; vs3 += d - rsD[old];
        rsA[s8] = a; rsB[s8] = b; rsC[s8] = c; rsD[s8] = d;
        srm[s8] = l3; sr0[s8] = q0; sr1[s8] = q1; sr2[s8] = q2; sr3[s8] = q3; srp[s8] = r0;
        if (doEmit) {                                // emit row Y = band + m - 6
            float wf0, wf1, wf2, wf3;
            if (EDGE) {
                const int Y = band + m - 6;
                float fy = (float)(7 - max(0, 3 - Y) - max(0, Y - (H - 4)));
                wf0 = fy * wfxc0; wf1 = fy * wfxc1; wf2 = fy * wfxc2; wf3 = fy * wfxc3;
            } else {
                wf0 = wf70; wf1 = wf71; wf2 = wf72; wf3 = wf73;
            }
            const int sA = (s8 + 4) & 7, sB = (s8 + 5) & 7, sC = (s8 + 6) & 7;
            float A0 = srm[sA], A1 = sr0[sA], A2 = sr1[sA], A3 = sr2[sA], A4 = sr3[sA], A5 = srp[sA];
            float B0 = srm[sB], B1 = sr0[sB], B2 = sr1[sB], B3 = sr2[sB], B4 = sr3[sB], B5 = srp[sB];
            float C0 = srm[sC], C1 = sr0[sC], C2 = sr1[sC], C3 = sr2[sC], C4 = sr3[sC], C5 = srp[sC];
            float t0 = A0 + C0, t1 = A1 + C1, t2 = A2 + C2, t3 = A3 + C3, t4 = A4 + C4, t5 = A5 + C5;
            float u0 = A0 - C0, u1 = A1 - C1, u2 = A2 - C2, u3 = A3 - C3, u4 = A4 - C4, u5 = A5 - C5;
            auto PIXF = [&](float tp, float tp1, float tp2, float Bp, float Bp1, float Bp2,
                            float up, float up1, float up2, float vsv, float wf) {
                float sgx = (tp - tp2) + 2.f * (Bp - Bp2);
                float sgy = (up + up2) + 2.f * up1;
                float lp  = (Bp + Bp2) + tp1 - 4.f * Bp1;
                float edge = __builtin_amdgcn_sqrtf(sgx * sgx + sgy * sgy) + 0.5f * fabsf(lp);
                float dd = Bp1 - vsv * (1.f / 49.f);
                acc += ALPHA * edge + wf * (dd * dd);
            };
            PIXF(t0, t1, t2, B0, B1, B2, u0, u1, u2, vs0, wf0);
            PIXF(t1, t2, t3, B1, B2, B3, u1, u2, u3, vs1, wf1);
            PIXF(t2, t3, t4, B2, B3, B4, u2, u3, u4, vs2, wf2);
            PIXF(t3, t4, t5, B3, B4, B5, u3, u4, u5, vs3, wf3);
        }
    };

    // pair: ingest rows n and n+1 (global rows g, g+1), one barrier.
    // vb slots: n&7 / (n+1)&7; refilled with rows g+8/g+9 (consumed at pair n+8).
    auto PAIR = [&](int n, bool doEmit, bool doLoad) {
        const int g    = band - 3 + n;
        const int sv0  = n & 7, sv1 = (n + 1) & 7;   // vb slots
        const int sl0  = n & 3, sl1 = (n + 1) & 3;   // lrow slots
        float4 raw0 = vb[sv0];
        float4 raw1 = vb[sv1];
        if (doLoad) { LOADROW(g + 8, sv0); LOADROW(g + 9, sv1); }   // issue early
        float p0, p1, p2, p3, q0, q1, q2, q3;
        if (EDGE) {
            p0 = p1 = p2 = p3 = q0 = q1 = q2 = q3 = 0.f;
            if (g >= 0 && g < H) {
                p0 = sigf(raw0.x); p1 = sigf(raw0.y); p2 = sigf(raw0.z); p3 = sigf(raw0.w);
            }
            if (g + 1 >= 0 && g + 1 < H) {
                q0 = sigf(raw1.x); q1 = sigf(raw1.y); q2 = sigf(raw1.z); q3 = sigf(raw1.w);
            }
        } else {
            p0 = sigf(raw0.x); p1 = sigf(raw0.y); p2 = sigf(raw0.z); p3 = sigf(raw0.w);
            q0 = sigf(raw1.x); q1 = sigf(raw1.y); q2 = sigf(raw1.z); q3 = sigf(raw1.w);
        }
        *(float4*)&lrow[sl0][c4 + 4] = make_float4(p0, p1, p2, p3);
        *(float4*)&lrow[sl1][c4 + 4] = make_float4(q0, q1, q2, q3);
        block_sync_lds();
        INGEST(n,     p0, p1, p2, p3, sl0, doEmit);
        INGEST(n + 1, q0, q1, q2, q3, sl1, doEmit);
    };

    // ingest rows band-3 .. band+66 (70 rows = 35 pairs); emit band .. band+63.
    // Pair 62's refill (rows band+67/68) is dead but in-range for all bands.
    #pragma unroll
    for (int i = 0; i < 8; ++i) LOADROW(band - 3 + i, i);
    PAIR(0, false, true);
    PAIR(2, false, true);
    PAIR(4, false, true);
    PAIR(6, true,  true);
    #pragma unroll 1
    for (int nn = 8; nn <= 56; nn += 8) {            // pairs 8..62; slots constant per k
        PAIR(nn + 0, true, true);
        PAIR(nn + 2, true, true);
        PAIR(nn + 4, true, true);
        PAIR(nn + 6, true, true);
    }
    PAIR(64, true, false);                           // consume slots filled at pairs 56/58/60
    PAIR(66, true, false);
    PAIR(68, true, false);

    return acc;
}

__global__ __launch_bounds__(256, 3)
void score_kernel(const float* __restrict__ logits, float* __restrict__ scores_ws) {
    __shared__ __align__(16) float lrow[4][1032];   // col c at idx c+4; borders zero
    __shared__ float red[4];
    const int tid  = threadIdx.x;
    const int lane = tid & 63;
    const int wvi  = tid >> 6;
    const int ch   = blockIdx.y;
    const int band = blockIdx.x * BH;
    const int c4   = wvi * 256 + lane * 4;
    const float* gbase = logits + (size_t)ch * (H * W) + c4;

    if (tid < 32) {                                  // zero 4 slots' borders once
        int s   = tid >> 3;
        int idx = (tid & 3) + ((tid & 4) ? 1028 : 0);
        lrow[s][idx] = 0.f;
    }

    const float cvar  = (1.0f - ALPHA) * (1.0f / 49.0f);
    const float wfxc0 = cvar * (float)(7 - max(0, 3 - (c4 + 0)) - max(0, (c4 + 0) - (W - 4)));
    const float wfxc1 = cvar * (float)(7 - max(0, 3 - (c4 + 1)) - max(0, (c4 + 1) - (W - 4)));
    const float wfxc2 = cvar * (float)(7 - max(0, 3 - (c4 + 2)) - max(0, (c4 + 2) - (W - 4)));
    const float wfxc3 = cvar * (float)(7 - max(0, 3 - (c4 + 3)) - max(0, (c4 + 3) - (W - 4)));

    float acc;
    if (blockIdx.x == 0 || blockIdx.x == gridDim.x - 1)
        acc = score_walk<true >(gbase, lrow, band, c4, wfxc0, wfxc1, wfxc2, wfxc3);
    else
        acc = score_walk<false>(gbase, lrow, band, c4, wfxc0, wfxc1, wfxc2, wfxc3);

    #pragma unroll
    for (int off = 32; off > 0; off >>= 1) acc += __shfl_down(acc, off);
    if (lane == 0) red[wvi] = acc;
    __syncthreads();
    if (tid == 0)
        scores_ws[ch * NBANDS + blockIdx.x] = red[0] + red[1] + red[2] + red[3];
}

// ---------------------------------------------------------------------------
// fuse_kernel: byte-identical to round 4 (attribution control).
// ---------------------------------------------------------------------------
__global__ __launch_bounds__(256)
void fuse_kernel(const float* __restrict__ logits,
                 const float* __restrict__ scores_ws,
                 const float* __restrict__ lw,
                 float* __restrict__ out) {
    const size_t HW4 = (size_t)(H * W) / 4;          // 2^18 float4 per plane

    const int b = blockIdx.x >> 8;                   // 4096 blocks, 1024 f4/block
    const float* sp = scores_ws + (size_t)b * 3 * NBANDS;
    float s0 = 0.f, s1 = 0.f, s2 = 0.f;
    #pragma unroll
    for (int i = 0; i < NBANDS; ++i) {
        s0 += sp[i];
        s1 += sp[NBANDS + i];
        s2 += sp[2 * NBANDS + i];
    }

    float l0 = lw[0], l1 = lw[1], l2 = lw[2];
    float mx = fmaxf(l0, fmaxf(l1, l2));
    float e0 = __expf(l0 - mx), e1 = __expf(l1 - mx), e2 = __expf(l2 - mx);
    float inv = __builtin_amdgcn_rcpf(e0 + e1 + e2);
    float itot = __builtin_amdgcn_rcpf(s0 + s1 + s2 + 1e-6f);
    float w0 = 0.5f * (s0 * itot + e0 * inv);
    float w1 = 0.5f * (s1 * itot + e1 * inv);
    float w2 = 0.5f * (s2 * itot + e2 * inv);

    size_t i0 = (size_t)blockIdx.x * 1024 + threadIdx.x;
    size_t r  = i0 & (HW4 - 1);
    const nfloat4* pb = (const nfloat4*)logits + (size_t)b * 3 * HW4 + r;
    nfloat4* po = (nfloat4*)out + i0;
    #pragma unroll
    for (int k = 0; k < 4; ++k) {
        nfloat4 x0 = pb[k * 256];
        nfloat4 x1 = pb[k * 256 + HW4];
        nfloat4 x2 = pb[k * 256 + 2 * HW4];
        nfloat4 o = x0 * w0 + x1 * w1 + x2 * w2;
        __builtin_nontemporal_store(o, po + k * 256);
    }
}

extern "C" void kernel_launch(void* const* d_in, const int* in_sizes, int n_in,
                              void* d_out, int out_size, void* d_ws, size_t ws_size,
                              hipStream_t stream) {
    const float* logits = (const float*)d_in[0];
    const float* lw     = (const float*)d_in[1];
    float* out       = (float*)d_out;
    float* scores_ws = (float*)d_ws;   // 48*16 floats, fully rewritten each run

    dim3 g1(NBANDS, NCH);              // (16, 48) = 768 blocks
    score_kernel<<<g1, 256, 0, stream>>>(logits, scores_ws);
    // INSTRUMENTATION (this round only): score is idempotent; the second
    // launch's cost = Delta(total vs round 4) ~= warm score duration. Gives
    // per-kernel attribution that rocprof's top-5 (masked by ~120us harness
    // fills) cannot. Round 6 removes it and banks the measurement.
    score_kernel<<<g1, 256, 0, stream>>>(logits, scores_ws);

    fuse_kernel<<<4096, 256, 0, stream>>>(logits, scores_ws, lw, out);
}

// Round 7
// 410.567 us; speedup vs baseline: 1.3027x; 1.3027x over previous
//
#include <hip/hip_runtime.h>
#include <math.h>

#define ALPHA 0.42f
#define H 1024
#define W 1024
#define NCH 48
#define BH 64
#define NBANDS (H / BH)     // 16 bands; grid (16,48) = 768 blocks -> 3/CU, one clean round

typedef float nfloat4 __attribute__((ext_vector_type(4)));

__device__ __forceinline__ float sigf(float x) {
    return __builtin_amdgcn_rcpf(1.0f + __expf(-x));
}

// LDS handoff barrier that does NOT drain vmcnt: keeps the global prefetch
// ring in flight across the barrier. lgkmcnt(0) retires this wave's ds ops.
__device__ __forceinline__ void block_sync_lds() {
    asm volatile("s_waitcnt lgkmcnt(0)" ::: "memory");
    __builtin_amdgcn_s_barrier();
    asm volatile("" ::: "memory");
}

// ---------------------------------------------------------------------------
// score walk, templated on EDGE (interior bands skip clamps/validity/fy).
// RULE-#20 DISCIPLINE: every array index (vb ring, lrow slot, sr*/rs* ring
// slot) is a LITERAL at every call site, passed down as arguments from
// unrolled code. Rounds 4/5 computed slots from runtime n inside the lambdas
// -> SROA demoted the rings to scratch (WRITE_SIZE 234 MB, 173 us). Round 1's
// literal-slot pattern measured clean (WRITE 48 KB). Never index by runtime n.
// ---------------------------------------------------------------------------
template<bool EDGE>
__device__ __forceinline__ float score_walk(const float* __restrict__ gbase,
                                            float (*lrow)[1032],
                                            const int band, const int c4,
                                            const float wfxc0, const float wfxc1,
                                            const float wfxc2, const float wfxc3)
{
    float4 vb[8];                                    // global prefetch ring, depth 8
    float srm[8], sr0[8], sr1[8], sr2[8], sr3[8], srp[8];
    float rsA[8], rsB[8], rsC[8], rsD[8];
    float vs0 = 0.f, vs1 = 0.f, vs2 = 0.f, vs3 = 0.f, acc = 0.f;
    #pragma unroll
    for (int k = 0; k < 8; ++k) { rsA[k] = rsB[k] = rsC[k] = rsD[k] = 0.f; }

    const float wf70 = 7.f * wfxc0, wf71 = 7.f * wfxc1;
    const float wf72 = 7.f * wfxc2, wf73 = 7.f * wfxc3;

    // slot is literal at every call site
    auto LOADROW = [&](int g, int slot) {
        int gc = EDGE ? min(max(g, 0), H - 1) : g;   // interior rows always in-range
        vb[slot] = *(const float4*)(gbase + ((size_t)gc << 10));
    };

    // m: runtime row counter (arithmetic only); s8, sl: literal slots
    auto INGEST = [&](int m, int s8, float q0, float q1, float q2, float q3,
                      int sl, bool doEmit) {
        float4 hl = *(const float4*)&lrow[sl][c4];       // cols c4-4..c4-1
        float4 hr = *(const float4*)&lrow[sl][c4 + 8];   // cols c4+4..c4+7
        float l1 = hl.y, l2 = hl.z, l3 = hl.w;
        float r0 = hr.x, r1 = hr.y, r2 = hr.z;
        float a = ((l1 + l2) + (l3 + q0)) + ((q1 + q2) + q3);
        float b = a - l1 + r0;
        float c = b - l2 + r1;
        float d = c - l3 + r2;
        const int old = (s8 + 1) & 7;                // literal-derived
        vs0 += a - rsA[old]; vs1 += b - rsB[old]; vs2 += c - rsC[old]; vs3 += d - rsD[old];
        rsA[s8] = a; rsB[s8] = b; rsC[s8] = c; rsD[s8] = d;
        srm[s8] = l3; sr0[s8] = q0; sr1[s8] = q1; sr2[s8] = q2; sr3[s8] = q3; srp[s8] = r0;
        if (doEmit) {                                // emit row Y = band + m - 6
            float wf0, wf1, wf2, wf3;
            if (EDGE) {
                const int Y = band + m - 6;
                float fy = (float)(7 - max(0, 3 - Y) - max(0, Y - (H - 4)));
                wf0 = fy * wfxc0; wf1 = fy * wfxc1; wf2 = fy * wfxc2; wf3 = fy * wfxc3;
            } else {
                wf0 = wf70; wf1 = wf71; wf2 = wf72; wf3 = wf73;
            }
            const int sA = (s8 + 4) & 7, sB = (s8 + 5) & 7, sC = (s8 + 6) & 7;
            float A0 = srm[sA], A1 = sr0[sA], A2 = sr1[sA], A3 = sr2[sA], A4 = sr3[sA], A5 = srp[sA];
            float B0 = srm[sB], B1 = sr0[sB], B2 = sr1[sB], B3 = sr2[sB], B4 = sr3[sB], B5 = srp[sB];
            float C0 = srm[sC], C1 = sr0[sC], C2 = sr1[sC], C3 = sr2[sC], C4 = sr3[sC], C5 = srp[sC];
            float t0 = A0 + C0, t1 = A1 + C1, t2 = A2 + C2, t3 = A3 + C3, t4 = A4 + C4, t5 = A5 + C5;
            float u0 = A0 - C0, u1 = A1 - C1, u2 = A2 - C2, u3 = A3 - C3, u4 = A4 - C4, u5 = A5 - C5;
            auto PIXF = [&](float tp, float tp1, float tp2, float Bp, float Bp1, float Bp2,
                            float up, float up1, float up2, float vsv, float wf) {
                float sgx = (tp - tp2) + 2.f * (Bp - Bp2);
                float sgy = (up + up2) + 2.f * up1;
                float lp  = (Bp + Bp2) + tp1 - 4.f * Bp1;
                float edge = __builtin_amdgcn_sqrtf(sgx * sgx + sgy * sgy) + 0.5f * fabsf(lp);
                float dd = Bp1 - vsv * (1.f / 49.f);
                acc += ALPHA * edge + wf * (dd * dd);
            };
            PIXF(t0, t1, t2, B0, B1, B2, u0, u1, u2, vs0, wf0);
            PIXF(t1, t2, t3, B1, B2, B3, u1, u2, u3, vs1, wf1);
            PIXF(t2, t3, t4, B2, B3, B4, u2, u3, u4, vs2, wf2);
            PIXF(t3, t4, t5, B3, B4, B5, u3, u4, u5, vs3, wf3);
        }
    };

    // pair: ingest rows n, n+1; one barrier. k2 = n&7 passed as a LITERAL.
    // vb slots k2/k2+1 refilled with rows g+8/g+9 (consumed 4 pairs later).
    auto PAIR = [&](int n, int k2, bool doEmit, bool doLoad) {
        const int g = band - 3 + n;
        float4 raw0 = vb[k2];
        float4 raw1 = vb[k2 + 1];
        if (doLoad) { LOADROW(g + 8, k2); LOADROW(g + 9, k2 + 1); }   // issue early
        float p0, p1, p2, p3, q0, q1, q2, q3;
        if (EDGE) {
            p0 = p1 = p2 = p3 = q0 = q1 = q2 = q3 = 0.f;
            if (g >= 0 && g < H) {
                p0 = sigf(raw0.x); p1 = sigf(raw0.y); p2 = sigf(raw0.z); p3 = sigf(raw0.w);
            }
            if (g + 1 >= 0 && g + 1 < H) {
                q0 = sigf(raw1.x); q1 = sigf(raw1.y); q2 = sigf(raw1.z); q3 = sigf(raw1.w);
            }
        } else {
            p0 = sigf(raw0.x); p1 = sigf(raw0.y); p2 = sigf(raw0.z); p3 = sigf(raw0.w);
            q0 = sigf(raw1.x); q1 = sigf(raw1.y); q2 = sigf(raw1.z); q3 = sigf(raw1.w);
        }
        *(float4*)&lrow[k2 & 3][c4 + 4]       = make_float4(p0, p1, p2, p3);
        *(float4*)&lrow[(k2 + 1) & 3][c4 + 4] = make_float4(q0, q1, q2, q3);
        block_sync_lds();
        INGEST(n,     k2,     p0, p1, p2, p3, k2 & 3,       doEmit);
        INGEST(n + 1, k2 + 1, q0, q1, q2, q3, (k2 + 1) & 3, doEmit);
    };

    // ingest rows band-3 .. band+66 (70 rows = 35 pairs); emit band .. band+63.
    // Pair 62's refill (rows band+67/68) is dead but in-range for all bands.
    #pragma unroll
    for (int i = 0; i < 8; ++i) LOADROW(band - 3 + i, i);   // i literal by unroll
    PAIR(0, 0, false, true);
    PAIR(2, 2, false, true);
    PAIR(4, 4, false, true);
    PAIR(6, 6, true,  true);
    #pragma unroll 1
    for (int nn = 8; nn <= 56; nn += 8) {            // pairs 8..62; k2 literal per call
        PAIR(nn + 0, 0, true, true);
        PAIR(nn + 2, 2, true, true);
        PAIR(nn + 4, 4, true, true);
        PAIR(nn + 6, 6, true, true);
    }
    PAIR(64, 0, true, false);                        // consume slots from pairs 56/58/60
    PAIR(66, 2, true, false);
    PAIR(68, 4, true, false);

    return acc;
}

__global__ __launch_bounds__(256, 3)
void score_kernel(const float* __restrict__ logits, float* __restrict__ scores_ws) {
    __shared__ __align__(16) float lrow[4][1032];   // col c at idx c+4; borders zero
    __shared__ float red[4];
    const int tid  = threadIdx.x;
    const int lane = tid & 63;
    const int wvi  = tid >> 6;
    const int ch   = blockIdx.y;
    const int band = blockIdx.x * BH;
    const int c4   = wvi * 256 + lane * 4;
    const float* gbase = logits + (size_t)ch * (H * W) + c4;

    if (tid < 32) {                                  // zero 4 slots' borders once
        int s   = tid >> 3;
        int idx = (tid & 3) + ((tid & 4) ? 1028 : 0);
        lrow[s][idx] = 0.f;
    }

    const float cvar  = (1.0f - ALPHA) * (1.0f / 49.0f);
    const float wfxc0 = cvar * (float)(7 - max(0, 3 - (c4 + 0)) - max(0, (c4 + 0) - (W - 4)));
    const float wfxc1 = cvar * (float)(7 - max(0, 3 - (c4 + 1)) - max(0, (c4 + 1) - (W - 4)));
    const float wfxc2 = cvar * (float)(7 - max(0, 3 - (c4 + 2)) - max(0, (c4 + 2) - (W - 4)));
    const float wfxc3 = cvar * (float)(7 - max(0, 3 - (c4 + 3)) - max(0, (c4 + 3) - (W - 4)));

    float acc;
    if (blockIdx.x == 0 || blockIdx.x == gridDim.x - 1)
        acc = score_walk<true >(gbase, lrow, band, c4, wfxc0, wfxc1, wfxc2, wfxc3);
    else
        acc = score_walk<false>(gbase, lrow, band, c4, wfxc0, wfxc1, wfxc2, wfxc3);

    #pragma unroll
    for (int off = 32; off > 0; off >>= 1) acc += __shfl_down(acc, off);
    if (lane == 0) red[wvi] = acc;
    __syncthreads();
    if (tid == 0)
        scores_ws[ch * NBANDS + blockIdx.x] = red[0] + red[1] + red[2] + red[3];
}

// ---------------------------------------------------------------------------
// fuse_kernel: byte-identical to rounds 4/5 (attribution control).
// ---------------------------------------------------------------------------
__global__ __launch_bounds__(256)
void fuse_kernel(const float* __restrict__ logits,
                 const float* __restrict__ scores_ws,
                 const float* __restrict__ lw,
                 float* __restrict__ out) {
    const size_t HW4 = (size_t)(H * W) / 4;          // 2^18 float4 per plane

    const int b = blockIdx.x >> 8;                   // 4096 blocks, 1024 f4/block
    const float* sp = scores_ws + (size_t)b * 3 * NBANDS;
    float s0 = 0.f, s1 = 0.f, s2 = 0.f;
    #pragma unroll
    for (int i = 0; i < NBANDS; ++i) {
        s0 += sp[i];
        s1 += sp[NBANDS + i];
        s2 += sp[2 * NBANDS + i];
    }

    float l0 = lw[0], l1 = lw[1], l2 = lw[2];
    float mx = fmaxf(l0, fmaxf(l1, l2));
    float e0 = __expf(l0 - mx), e1 = __expf(l1 - mx), e2 = __expf(l2 - mx);
    float inv = __builtin_amdgcn_rcpf(e0 + e1 + e2);
    float itot = __builtin_amdgcn_rcpf(s0 + s1 + s2 + 1e-6f);
    float w0 = 0.5f * (s0 * itot + e0 * inv);
    float w1 = 0.5f * (s1 * itot + e1 * inv);
    float w2 = 0.5f * (s2 * itot + e2 * inv);

    size_t i0 = (size_t)blockIdx.x * 1024 + threadIdx.x;
    size_t r  = i0 & (HW4 - 1);
    const nfloat4* pb = (const nfloat4*)logits + (size_t)b * 3 * HW4 + r;
    nfloat4* po = (nfloat4*)out + i0;
    #pragma unroll
    for (int k = 0; k < 4; ++k) {
        nfloat4 x0 = pb[k * 256];
        nfloat4 x1 = pb[k * 256 + HW4];
        nfloat4 x2 = pb[k * 256 + 2 * HW4];
        nfloat4 o = x0 * w0 + x1 * w1 + x2 * w2;
        __builtin_nontemporal_store(o, po + k * 256);
    }
}

extern "C" void kernel_launch(void* const* d_in, const int* in_sizes, int n_in,
                              void* d_out, int out_size, void* d_ws, size_t ws_size,
                              hipStream_t stream) {
    const float* logits = (const float*)d_in[0];
    const float* lw     = (const float*)d_in[1];
    float* out       = (float*)d_out;
    float* scores_ws = (float*)d_ws;   // 48*16 floats, fully rewritten each run

    dim3 g1(NBANDS, NCH);              // (16, 48) = 768 blocks
    score_kernel<<<g1, 256, 0, stream>>>(logits, scores_ws);

    fuse_kernel<<<4096, 256, 0, stream>>>(logits, scores_ws, lw, out);
}

// Round 8
// 383.225 us; speedup vs baseline: 1.3957x; 1.0713x over previous
//
#include <hip/hip_runtime.h>
#include <math.h>

#define ALPHA 0.42f
#define H 1024
#define W 1024
#define NCH 48
#define BH 64
#define NBANDS (H / BH)     // 16 bands; grid (16,48) = 768 blocks -> 3/CU, one clean round

typedef float nfloat4 __attribute__((ext_vector_type(4)));

__device__ __forceinline__ float sigf(float x) {
    return __builtin_amdgcn_rcpf(1.0f + __expf(-x));
}

// LDS handoff barrier that does NOT drain vmcnt: keeps the global prefetch
// ring in flight across the barrier. lgkmcnt(0) retires this wave's ds ops.
__device__ __forceinline__ void block_sync_lds() {
    asm volatile("s_waitcnt lgkmcnt(0)" ::: "memory");
    __builtin_amdgcn_s_barrier();
    asm volatile("" ::: "memory");
}

// ---------------------------------------------------------------------------
// score_kernel v8: VGPR-capacity-driven redesign.
// launch_bounds(256,3) caps VGPR at 128 (occupancy tier). Rounds 5/7 kept
// ~145 regs of rings -> allocator spilled arrays wholesale (WRITE_SIZE 230MB,
// 173us) regardless of literal indexing. Fix: the six sigmoid-row rings
// (48 VGPRs) are ELIMINATED — the LDS row ring is deepened to 8 slots and
// EMIT re-reads its 3 stencil rows from LDS. Register set: vb[4](16) +
// rs rings(32) + temps ~= 100 < 128 -> no spill at 3 blocks/CU.
// Ring safety: slot s (= step & 7) is written pre-barrier at step s; read by
// halo at step s and by emits at steps s+2..s+4; those reads retire at the
// lgkmcnt(0) of the following pair-barrier; rewrite happens at step s+8,
// >= 2 barriers later -> no race.
// ---------------------------------------------------------------------------
__global__ __launch_bounds__(256, 3)
void score_kernel(const float* __restrict__ logits, float* __restrict__ scores_ws) {
    __shared__ __align__(16) float lrow[8][1032];   // col c at idx c+4; borders zero
    __shared__ float red[4];
    const int tid  = threadIdx.x;
    const int lane = tid & 63;
    const int wvi  = tid >> 6;
    const int ch   = blockIdx.y;
    const int band = blockIdx.x * BH;
    const int c4   = wvi * 256 + lane * 4;
    const float* gbase = logits + (size_t)ch * (H * W) + c4;

    if (tid < 64) {                                  // zero 8 slots' borders once
        int s   = tid >> 3;
        int idx = (tid & 3) + ((tid & 4) ? 1028 : 0);
        lrow[s][idx] = 0.f;
    }

    const float cvar  = (1.0f - ALPHA) * (1.0f / 49.0f);
    const float wfxc0 = cvar * (float)(7 - max(0, 3 - (c4 + 0)) - max(0, (c4 + 0) - (W - 4)));
    const float wfxc1 = cvar * (float)(7 - max(0, 3 - (c4 + 1)) - max(0, (c4 + 1) - (W - 4)));
    const float wfxc2 = cvar * (float)(7 - max(0, 3 - (c4 + 2)) - max(0, (c4 + 2) - (W - 4)));
    const float wfxc3 = cvar * (float)(7 - max(0, 3 - (c4 + 3)) - max(0, (c4 + 3) - (W - 4)));

    float4 vb[4];                                    // global prefetch ring, depth 4
    float rsA[8], rsB[8], rsC[8], rsD[8];            // horizontal 7-sum ring (the only big ring)
    float vs0 = 0.f, vs1 = 0.f, vs2 = 0.f, vs3 = 0.f, acc = 0.f;
    #pragma unroll
    for (int k = 0; k < 8; ++k) { rsA[k] = rsB[k] = rsC[k] = rsD[k] = 0.f; }

    auto LOADROW = [&](int g, int slot) {            // slot literal at call sites
        int gc = min(max(g, 0), H - 1);
        vb[slot] = *(const float4*)(gbase + ((size_t)gc << 10));
    };

    // read one stencil row (cols c4-1 .. c4+4) from LDS slot s
    auto ROW6 = [&](int s, float& v0, float& v1, float& v2, float& v3, float& v4, float& v5) {
        float4 mid = *(const float4*)&lrow[s][c4 + 4];   // cols c4..c4+3
        v0 = lrow[s][c4 + 3];                             // col c4-1
        v5 = lrow[s][c4 + 8];                             // col c4+4
        v1 = mid.x; v2 = mid.y; v3 = mid.z; v4 = mid.w;
    };

    // post-barrier work for one row; n runtime (arithmetic only), s8 literal
    auto INGEST = [&](int n, int s8, float q0, float q1, float q2, float q3, bool doEmit) {
        float4 hl = *(const float4*)&lrow[s8][c4];       // cols c4-4..c4-1
        float4 hr = *(const float4*)&lrow[s8][c4 + 8];   // cols c4+4..c4+7
        float l1 = hl.y, l2 = hl.z, l3 = hl.w;
        float r0 = hr.x, r1 = hr.y, r2 = hr.z;
        float a = ((l1 + l2) + (l3 + q0)) + ((q1 + q2) + q3);
        float b = a - l1 + r0;
        float c = b - l2 + r1;
        float d = c - l3 + r2;
        const int old = (s8 + 1) & 7;
        vs0 += a - rsA[old]; vs1 += b - rsB[old]; vs2 += c - rsC[old]; vs3 += d - rsD[old];
        rsA[s8] = a; rsB[s8] = b; rsC[s8] = c; rsD[s8] = d;
        if (doEmit) {                                // emit row Y = band + n - 6
            const int Y = band + n - 6;
            float fy = (float)(7 - max(0, 3 - Y) - max(0, Y - (H - 4)));
            float wf0 = fy * wfxc0, wf1 = fy * wfxc1, wf2 = fy * wfxc2, wf3 = fy * wfxc3;
            float A0, A1, A2, A3, A4, A5, B0, B1, B2, B3, B4, B5, C0, C1, C2, C3, C4, C5;
            ROW6((s8 + 4) & 7, A0, A1, A2, A3, A4, A5);  // step n-4 -> row Y-1
            ROW6((s8 + 5) & 7, B0, B1, B2, B3, B4, B5);  // step n-3 -> row Y
            ROW6((s8 + 6) & 7, C0, C1, C2, C3, C4, C5);  // step n-2 -> row Y+1
            float t0 = A0 + C0, t1 = A1 + C1, t2 = A2 + C2, t3 = A3 + C3, t4 = A4 + C4, t5 = A5 + C5;
            float u0 = A0 - C0, u1 = A1 - C1, u2 = A2 - C2, u3 = A3 - C3, u4 = A4 - C4, u5 = A5 - C5;
            auto PIXF = [&](float tp, float tp1, float tp2, float Bp, float Bp1, float Bp2,
                            float up, float up1, float up2, float vsv, float wf) {
                float sgx = (tp - tp2) + 2.f * (Bp - Bp2);
                float sgy = (up + up2) + 2.f * up1;
                float lp  = (Bp + Bp2) + tp1 - 4.f * Bp1;
                float edge = __builtin_amdgcn_sqrtf(sgx * sgx + sgy * sgy) + 0.5f * fabsf(lp);
                float dd = Bp1 - vsv * (1.f / 49.f);
                acc += ALPHA * edge + wf * (dd * dd);
            };
            PIXF(t0, t1, t2, B0, B1, B2, u0, u1, u2, vs0, wf0);
            PIXF(t1, t2, t3, B1, B2, B3, u1, u2, u3, vs1, wf1);
            PIXF(t2, t3, t4, B2, B3, B4, u2, u3, u4, vs2, wf2);
            PIXF(t3, t4, t5, B3, B4, B5, u3, u4, u5, vs3, wf3);
        }
    };

    // pair: ingest rows n, n+1 (global rows g, g+1); ONE barrier.
    // s8a/s8b (= n&7, n+1&7) and sva/svb (= n&3, n+1&3) literal at call sites.
    auto PAIR = [&](int n, int s8a, int s8b, int sva, int svb, bool doEmit, bool doLoad) {
        const int g = band - 3 + n;
        float4 raw0 = vb[sva];
        float4 raw1 = vb[svb];
        if (doLoad) { LOADROW(g + 4, sva); LOADROW(g + 5, svb); }   // issue early
        float p0 = 0.f, p1 = 0.f, p2 = 0.f, p3 = 0.f;
        float q0 = 0.f, q1 = 0.f, q2 = 0.f, q3 = 0.f;
        if (g >= 0 && g < H) {
            p0 = sigf(raw0.x); p1 = sigf(raw0.y); p2 = sigf(raw0.z); p3 = sigf(raw0.w);
        }
        if (g + 1 >= 0 && g + 1 < H) {
            q0 = sigf(raw1.x); q1 = sigf(raw1.y); q2 = sigf(raw1.z); q3 = sigf(raw1.w);
        }
        *(float4*)&lrow[s8a][c4 + 4] = make_float4(p0, p1, p2, p3);
        *(float4*)&lrow[s8b][c4 + 4] = make_float4(q0, q1, q2, q3);
        block_sync_lds();
        INGEST(n,     s8a, p0, p1, p2, p3, doEmit);
        INGEST(n + 1, s8b, q0, q1, q2, q3, doEmit);
    };

    // ingest rows band-3 .. band+66 (70 rows = 35 pairs); emit band .. band+63
    LOADROW(band - 3, 0);
    LOADROW(band - 2, 1);
    LOADROW(band - 1, 2);
    LOADROW(band + 0, 3);
    PAIR(0, 0, 1, 0, 1, false, true);
    PAIR(2, 2, 3, 2, 3, false, true);
    PAIR(4, 4, 5, 0, 1, false, true);
    PAIR(6, 6, 7, 2, 3, true,  true);
    #pragma unroll 1
    for (int nn = 8; nn <= 56; nn += 8) {            // pairs 8..62; all slots literal
        PAIR(nn + 0, 0, 1, 0, 1, true, true);
        PAIR(nn + 2, 2, 3, 2, 3, true, true);
        PAIR(nn + 4, 4, 5, 0, 1, true, true);
        PAIR(nn + 6, 6, 7, 2, 3, true, true);
    }
    PAIR(64, 0, 1, 0, 1, true, true);                // loads band+65/66 for pair 68
    PAIR(66, 2, 3, 2, 3, true, false);
    PAIR(68, 4, 5, 0, 1, true, false);

    #pragma unroll
    for (int off = 32; off > 0; off >>= 1) acc += __shfl_down(acc, off);
    if (lane == 0) red[wvi] = acc;
    __syncthreads();
    if (tid == 0)
        scores_ws[ch * NBANDS + blockIdx.x] = red[0] + red[1] + red[2] + red[3];
}

// ---------------------------------------------------------------------------
// fuse_kernel: byte-identical to rounds 4-7 (attribution control).
// ---------------------------------------------------------------------------
__global__ __launch_bounds__(256)
void fuse_kernel(const float* __restrict__ logits,
                 const float* __restrict__ scores_ws,
                 const float* __restrict__ lw,
                 float* __restrict__ out) {
    const size_t HW4 = (size_t)(H * W) / 4;          // 2^18 float4 per plane

    const int b = blockIdx.x >> 8;                   // 4096 blocks, 1024 f4/block
    const float* sp = scores_ws + (size_t)b * 3 * NBANDS;
    float s0 = 0.f, s1 = 0.f, s2 = 0.f;
    #pragma unroll
    for (int i = 0; i < NBANDS; ++i) {
        s0 += sp[i];
        s1 += sp[NBANDS + i];
        s2 += sp[2 * NBANDS + i];
    }

    float l0 = lw[0], l1 = lw[1], l2 = lw[2];
    float mx = fmaxf(l0, fmaxf(l1, l2));
    float e0 = __expf(l0 - mx), e1 = __expf(l1 - mx), e2 = __expf(l2 - mx);
    float inv = __builtin_amdgcn_rcpf(e0 + e1 + e2);
    float itot = __builtin_amdgcn_rcpf(s0 + s1 + s2 + 1e-6f);
    float w0 = 0.5f * (s0 * itot + e0 * inv);
    float w1 = 0.5f * (s1 * itot + e1 * inv);
    float w2 = 0.5f * (s2 * itot + e2 * inv);

    size_t i0 = (size_t)blockIdx.x * 1024 + threadIdx.x;
    size_t r  = i0 & (HW4 - 1);
    const nfloat4* pb = (const nfloat4*)logits + (size_t)b * 3 * HW4 + r;
    nfloat4* po = (nfloat4*)out + i0;
    #pragma unroll
    for (int k = 0; k < 4; ++k) {
        nfloat4 x0 = pb[k * 256];
        nfloat4 x1 = pb[k * 256 + HW4];
        nfloat4 x2 = pb[k * 256 + 2 * HW4];
        nfloat4 o = x0 * w0 + x1 * w1 + x2 * w2;
        __builtin_nontemporal_store(o, po + k * 256);
    }
}

extern "C" void kernel_launch(void* const* d_in, const int* in_sizes, int n_in,
                              void* d_out, int out_size, void* d_ws, size_t ws_size,
                              hipStream_t stream) {
    const float* logits = (const float*)d_in[0];
    const float* lw     = (const float*)d_in[1];
    float* out       = (float*)d_out;
    float* scores_ws = (float*)d_ws;   // 48*16 floats, fully rewritten each run

    dim3 g1(NBANDS, NCH);              // (16, 48) = 768 blocks
    score_kernel<<<g1, 256, 0, stream>>>(logits, scores_ws);

    fuse_kernel<<<4096, 256, 0, stream>>>(logits, scores_ws, lw, out);
}

// Round 9
// 339.741 us; speedup vs baseline: 1.5743x; 1.1280x over previous
//
#include <hip/hip_runtime.h>
#include <math.h>

#define ALPHA 0.42f
#define H 1024
#define W 1024
#define NCH 48
#define BH 64
#define NBANDS (H / BH)     // 16 bands; grid (16,48) = 768 blocks

typedef float nfloat4 __attribute__((ext_vector_type(4)));

__device__ __forceinline__ float sigf(float x) {
    return __builtin_amdgcn_rcpf(1.0f + __expf(-x));
}

// LDS handoff barrier that does NOT drain vmcnt: keeps the global prefetch
// ring in flight across the barrier. lgkmcnt(0) retires this wave's ds ops.
__device__ __forceinline__ void block_sync_lds() {
    asm volatile("s_waitcnt lgkmcnt(0)" ::: "memory");
    __builtin_amdgcn_s_barrier();
    asm volatile("" ::: "memory");
}

// ---------------------------------------------------------------------------
// score_kernel v9 = v8 structure with the REAL register constraint fixed.
// Empirical allocator law (4 data points, rounds 0/3/5-8): hipcc budgets
// VGPRs for 2x the declared min-waves/EU:
//   (256,4) -> 64 regs, (256,3) -> 84, (256,2) -> 128.
// v8's ~100-reg working set could never fit 84 -> wholesale array spill
// (WRITE_SIZE 208 MB of scratch). (256,2) gives budget 128 -> spill-free;
// occupancy is then LDS-limited at 4 blocks/CU (33KB x 4 = 132KB < 160KB),
// BETTER than the spilling 3-block config.
// Also: EMIT's stencil-row reads are 3x ds_read_b128 (2-way conflicts free)
// instead of b128 + 2 scalar b32 at 16B stride (8-way conflict, 15.7M cnt).
// Ring safety: slot s written pre-barrier at step s; read at steps s..s+4;
// those reads retire at the next pair-barrier's lgkmcnt(0); rewrite at step
// s+8 is >=2 barriers later -> no race.
// ---------------------------------------------------------------------------
__global__ __launch_bounds__(256, 2)
void score_kernel(const float* __restrict__ logits, float* __restrict__ scores_ws) {
    __shared__ __align__(16) float lrow[8][1032];   // col c at idx c+4; borders zero
    __shared__ float red[4];
    const int tid  = threadIdx.x;
    const int lane = tid & 63;
    const int wvi  = tid >> 6;
    const int ch   = blockIdx.y;
    const int band = blockIdx.x * BH;
    const int c4   = wvi * 256 + lane * 4;
    const float* gbase = logits + (size_t)ch * (H * W) + c4;

    if (tid < 64) {                                  // zero 8 slots' borders once
        int s   = tid >> 3;
        int idx = (tid & 3) + ((tid & 4) ? 1028 : 0);
        lrow[s][idx] = 0.f;
    }

    const float cvar  = (1.0f - ALPHA) * (1.0f / 49.0f);
    const float wfxc0 = cvar * (float)(7 - max(0, 3 - (c4 + 0)) - max(0, (c4 + 0) - (W - 4)));
    const float wfxc1 = cvar * (float)(7 - max(0, 3 - (c4 + 1)) - max(0, (c4 + 1) - (W - 4)));
    const float wfxc2 = cvar * (float)(7 - max(0, 3 - (c4 + 2)) - max(0, (c4 + 2) - (W - 4)));
    const float wfxc3 = cvar * (float)(7 - max(0, 3 - (c4 + 3)) - max(0, (c4 + 3) - (W - 4)));

    float4 vb[4];                                    // global prefetch ring, depth 4
    float rsA[8], rsB[8], rsC[8], rsD[8];            // horizontal 7-sum ring
    float vs0 = 0.f, vs1 = 0.f, vs2 = 0.f, vs3 = 0.f, acc = 0.f;
    #pragma unroll
    for (int k = 0; k < 8; ++k) { rsA[k] = rsB[k] = rsC[k] = rsD[k] = 0.f; }

    auto LOADROW = [&](int g, int slot) {            // slot literal at call sites
        int gc = min(max(g, 0), H - 1);
        vb[slot] = *(const float4*)(gbase + ((size_t)gc << 10));
    };

    // read one stencil row (cols c4-1 .. c4+4) from LDS slot s: 3x b128 only
    auto ROW6 = [&](int s, float& v0, float& v1, float& v2, float& v3, float& v4, float& v5) {
        float4 a = *(const float4*)&lrow[s][c4];         // cols c4-4..c4-1
        float4 m = *(const float4*)&lrow[s][c4 + 4];     // cols c4..c4+3
        float4 b = *(const float4*)&lrow[s][c4 + 8];     // cols c4+4..c4+7
        v0 = a.w; v1 = m.x; v2 = m.y; v3 = m.z; v4 = m.w; v5 = b.x;
    };

    // post-barrier work for one row; n runtime (arithmetic only), s8 literal
    auto INGEST = [&](int n, int s8, float q0, float q1, float q2, float q3, bool doEmit) {
        float4 hl = *(const float4*)&lrow[s8][c4];       // cols c4-4..c4-1
        float4 hr = *(const float4*)&lrow[s8][c4 + 8];   // cols c4+4..c4+7
        float l1 = hl.y, l2 = hl.z, l3 = hl.w;
        float r0 = hr.x, r1 = hr.y, r2 = hr.z;
        float a = ((l1 + l2) + (l3 + q0)) + ((q1 + q2) + q3);
        float b = a - l1 + r0;
        float c = b - l2 + r1;
        float d = c - l3 + r2;
        const int old = (s8 + 1) & 7;
        vs0 += a - rsA[old]; vs1 += b - rsB[old]; vs2 += c - rsC[old]; vs3 += d - rsD[old];
        rsA[s8] = a; rsB[s8] = b; rsC[s8] = c; rsD[s8] = d;
        if (doEmit) {                                // emit row Y = band + n - 6
            const int Y = band + n - 6;
            float fy = (float)(7 - max(0, 3 - Y) - max(0, Y - (H - 4)));
            float wf0 = fy * wfxc0, wf1 = fy * wfxc1, wf2 = fy * wfxc2, wf3 = fy * wfxc3;
            float A0, A1, A2, A3, A4, A5, B0, B1, B2, B3, B4, B5, C0, C1, C2, C3, C4, C5;
            ROW6((s8 + 4) & 7, A0, A1, A2, A3, A4, A5);  // step n-4 -> row Y-1
            ROW6((s8 + 5) & 7, B0, B1, B2, B3, B4, B5);  // step n-3 -> row Y
            ROW6((s8 + 6) & 7, C0, C1, C2, C3, C4, C5);  // step n-2 -> row Y+1
            float t0 = A0 + C0, t1 = A1 + C1, t2 = A2 + C2, t3 = A3 + C3, t4 = A4 + C4, t5 = A5 + C5;
            float u0 = A0 - C0, u1 = A1 - C1, u2 = A2 - C2, u3 = A3 - C3, u4 = A4 - C4, u5 = A5 - C5;
            auto PIXF = [&](float tp, float tp1, float tp2, float Bp, float Bp1, float Bp2,
                            float up, float up1, float up2, float vsv, float wf) {
                float sgx = (tp - tp2) + 2.f * (Bp - Bp2);
                float sgy = (up + up2) + 2.f * up1;
                float lp  = (Bp + Bp2) + tp1 - 4.f * Bp1;
                float edge = __builtin_amdgcn_sqrtf(sgx * sgx + sgy * sgy) + 0.5f * fabsf(lp);
                float dd = Bp1 - vsv * (1.f / 49.f);
                acc += ALPHA * edge + wf * (dd * dd);
            };
            PIXF(t0, t1, t2, B0, B1, B2, u0, u1, u2, vs0, wf0);
            PIXF(t1, t2, t3, B1, B2, B3, u1, u2, u3, vs1, wf1);
            PIXF(t2, t3, t4, B2, B3, B4, u2, u3, u4, vs2, wf2);
            PIXF(t3, t4, t5, B3, B4, B5, u3, u4, u5, vs3, wf3);
        }
    };

    // pair: ingest rows n, n+1 (global rows g, g+1); ONE barrier.
    // s8a/s8b (= n&7, n+1&7) and sva/svb (= n&3, n+1&3) literal at call sites.
    auto PAIR = [&](int n, int s8a, int s8b, int sva, int svb, bool doEmit, bool doLoad) {
        const int g = band - 3 + n;
        float4 raw0 = vb[sva];
        float4 raw1 = vb[svb];
        if (doLoad) { LOADROW(g + 4, sva); LOADROW(g + 5, svb); }   // issue early
        float p0 = 0.f, p1 = 0.f, p2 = 0.f, p3 = 0.f;
        float q0 = 0.f, q1 = 0.f, q2 = 0.f, q3 = 0.f;
        if (g >= 0 && g < H) {
            p0 = sigf(raw0.x); p1 = sigf(raw0.y); p2 = sigf(raw0.z); p3 = sigf(raw0.w);
        }
        if (g + 1 >= 0 && g + 1 < H) {
            q0 = sigf(raw1.x); q1 = sigf(raw1.y); q2 = sigf(raw1.z); q3 = sigf(raw1.w);
        }
        *(float4*)&lrow[s8a][c4 + 4] = make_float4(p0, p1, p2, p3);
        *(float4*)&lrow[s8b][c4 + 4] = make_float4(q0, q1, q2, q3);
        block_sync_lds();
        INGEST(n,     s8a, p0, p1, p2, p3, doEmit);
        INGEST(n + 1, s8b, q0, q1, q2, q3, doEmit);
    };

    // ingest rows band-3 .. band+66 (70 rows = 35 pairs); emit band .. band+63
    LOADROW(band - 3, 0);
    LOADROW(band - 2, 1);
    LOADROW(band - 1, 2);
    LOADROW(band + 0, 3);
    PAIR(0, 0, 1, 0, 1, false, true);
    PAIR(2, 2, 3, 2, 3, false, true);
    PAIR(4, 4, 5, 0, 1, false, true);
    PAIR(6, 6, 7, 2, 3, true,  true);
    #pragma unroll 1
    for (int nn = 8; nn <= 56; nn += 8) {            // pairs 8..62; all slots literal
        PAIR(nn + 0, 0, 1, 0, 1, true, true);
        PAIR(nn + 2, 2, 3, 2, 3, true, true);
        PAIR(nn + 4, 4, 5, 0, 1, true, true);
        PAIR(nn + 6, 6, 7, 2, 3, true, true);
    }
    PAIR(64, 0, 1, 0, 1, true, true);                // loads band+65/66 for pair 68
    PAIR(66, 2, 3, 2, 3, true, false);
    PAIR(68, 4, 5, 0, 1, true, false);

    #pragma unroll
    for (int off = 32; off > 0; off >>= 1) acc += __shfl_down(acc, off);
    if (lane == 0) red[wvi] = acc;
    __syncthreads();
    if (tid == 0)
        scores_ws[ch * NBANDS + blockIdx.x] = red[0] + red[1] + red[2] + red[3];
}

// ---------------------------------------------------------------------------
// fuse_kernel: byte-identical to rounds 4-8 (attribution control).
// ---------------------------------------------------------------------------
__global__ __launch_bounds__(256)
void fuse_kernel(const float* __restrict__ logits,
                 const float* __restrict__ scores_ws,
                 const float* __restrict__ lw,
                 float* __restrict__ out) {
    const size_t HW4 = (size_t)(H * W) / 4;          // 2^18 float4 per plane

    const int b = blockIdx.x >> 8;                   // 4096 blocks, 1024 f4/block
    const float* sp = scores_ws + (size_t)b * 3 * NBANDS;
    float s0 = 0.f, s1 = 0.f, s2 = 0.f;
    #pragma unroll
    for (int i = 0; i < NBANDS; ++i) {
        s0 += sp[i];
        s1 += sp[NBANDS + i];
        s2 += sp[2 * NBANDS + i];
    }

    float l0 = lw[0], l1 = lw[1], l2 = lw[2];
    float mx = fmaxf(l0, fmaxf(l1, l2));
    float e0 = __expf(l0 - mx), e1 = __expf(l1 - mx), e2 = __expf(l2 - mx);
    float inv = __builtin_amdgcn_rcpf(e0 + e1 + e2);
    float itot = __builtin_amdgcn_rcpf(s0 + s1 + s2 + 1e-6f);
    float w0 = 0.5f * (s0 * itot + e0 * inv);
    float w1 = 0.5f * (s1 * itot + e1 * inv);
    float w2 = 0.5f * (s2 * itot + e2 * inv);

    size_t i0 = (size_t)blockIdx.x * 1024 + threadIdx.x;
    size_t r  = i0 & (HW4 - 1);
    const nfloat4* pb = (const nfloat4*)logits + (size_t)b * 3 * HW4 + r;
    nfloat4* po = (nfloat4*)out + i0;
    #pragma unroll
    for (int k = 0; k < 4; ++k) {
        nfloat4 x0 = pb[k * 256];
        nfloat4 x1 = pb[k * 256 + HW4];
        nfloat4 x2 = pb[k * 256 + 2 * HW4];
        nfloat4 o = x0 * w0 + x1 * w1 + x2 * w2;
        __builtin_nontemporal_store(o, po + k * 256);
    }
}

extern "C" void kernel_launch(void* const* d_in, const int* in_sizes, int n_in,
                              void* d_out, int out_size, void* d_ws, size_t ws_size,
                              hipStream_t stream) {
    const float* logits = (const float*)d_in[0];
    const float* lw     = (const float*)d_in[1];
    float* out       = (float*)d_out;
    float* scores_ws = (float*)d_ws;   // 48*16 floats, fully rewritten each run

    dim3 g1(NBANDS, NCH);              // (16, 48) = 768 blocks
    score_kernel<<<g1, 256, 0, stream>>>(logits, scores_ws);

    fuse_kernel<<<4096, 256, 0, stream>>>(logits, scores_ws, lw, out);
}

// Round 11
// 332.172 us; speedup vs baseline: 1.6102x; 1.0228x over previous
//
#include <hip/hip_runtime.h>
#include <math.h>

#define ALPHA 0.42f
#define H 1024
#define W 1024
#define NCH 48
#define BH 64
#define NBANDS (H / BH)     // 16 bands; grid (16,48) = 768 blocks -> 3/CU

typedef float nfloat4 __attribute__((ext_vector_type(4)));

__device__ __forceinline__ float sigf(float x) {
    return __builtin_amdgcn_rcpf(1.0f + __expf(-x));
}

// LDS handoff barrier that does NOT drain vmcnt: keeps the global prefetch
// ring in flight across the barrier. lgkmcnt(0) retires this wave's ds ops.
__device__ __forceinline__ void block_sync_lds() {
    asm volatile("s_waitcnt lgkmcnt(0)" ::: "memory");
    __builtin_amdgcn_s_barrier();
    asm volatile("" ::: "memory");
}

// ---------------------------------------------------------------------------
// score_kernel v10: LDS-traffic-driven redesign (v9 counters: spill fixed,
// but 12 b128/row through the per-CU LDS pipe + per-pair drains = the new
// bottleneck; conflicts 15.7M invariant, VALUBusy 37%, HBM 11%).
//   - EMIT reads come from 6 register rings (srm..srp, depth 8 = 48 VGPR),
//     NOT LDS re-reads: 9 fewer LDS ops/row, emit chain leaves the LDS pipe.
//   - horizontal 7-sum ring (a,b,c,d) moves to per-thread LDS scratch
//     rs_lds[8][tid] (tid-indexed -> private -> no barrier coupling),
//     freeing 32 VGPRs so the rings fit the (256,2)=128 budget law
//     (empirical: hipcc budget = 512 / (2*min_waves); (256,3) was 84).
//   - lrow halo ring shrinks to depth 4 (halo exchange only).
// Per-row LDS: 1 lrow write + 2 halo reads + 1 rs write + 1 rs read = 5 b128.
// Registers: rings 48 + vb[4] 16 + temps ~45 ~= 110 < 128 -> no spill.
// Ring safety (lrow): slot n&3 written pre-barrier step n, halo-read step n;
// reads retire at next pair's lgkmcnt(0); rewrite at n+4 is >=2 barriers
// later -> safe. rs_lds needs no barrier (same-thread only).
// ---------------------------------------------------------------------------
__global__ __launch_bounds__(256, 2)
void score_kernel(const float* __restrict__ logits, float* __restrict__ scores_ws) {
    __shared__ __align__(16) float lrow[4][1032];    // col c at idx c+4; borders zero
    __shared__ __align__(16) float4 rs_lds[8][256];  // per-thread 7-sum ring
    __shared__ float red[4];
    const int tid  = threadIdx.x;
    const int lane = tid & 63;
    const int wvi  = tid >> 6;
    const int ch   = blockIdx.y;
    const int band = blockIdx.x * BH;
    const int c4   = wvi * 256 + lane * 4;
    const float* gbase = logits + (size_t)ch * (H * W) + c4;

    #pragma unroll
    for (int s = 0; s < 8; ++s)                      // zero own rs scratch (no barrier needed)
        rs_lds[s][tid] = make_float4(0.f, 0.f, 0.f, 0.f);
    if (tid < 32) {                                  // zero 4 lrow slots' borders once
        int s   = tid >> 3;
        int idx = (tid & 3) + ((tid & 4) ? 1028 : 0);
        lrow[s][idx] = 0.f;
    }

    const float cvar  = (1.0f - ALPHA) * (1.0f / 49.0f);
    const float wfxc0 = cvar * (float)(7 - max(0, 3 - (c4 + 0)) - max(0, (c4 + 0) - (W - 4)));
    const float wfxc1 = cvar * (float)(7 - max(0, 3 - (c4 + 1)) - max(0, (c4 + 1) - (W - 4)));
    const float wfxc2 = cvar * (float)(7 - max(0, 3 - (c4 + 2)) - max(0, (c4 + 2) - (W - 4)));
    const float wfxc3 = cvar * (float)(7 - max(0, 3 - (c4 + 3)) - max(0, (c4 + 3) - (W - 4)));

    float4 vb[4];                                    // global prefetch ring, depth 4
    float srm[8], sr0[8], sr1[8], sr2[8], sr3[8], srp[8];  // sigmoid rows, cols c4-1..c4+4
    float vs0 = 0.f, vs1 = 0.f, vs2 = 0.f, vs3 = 0.f, acc = 0.f;

    auto LOADROW = [&](int g, int slot) {            // slot literal at call sites
        int gc = min(max(g, 0), H - 1);
        vb[slot] = *(const float4*)(gbase + ((size_t)gc << 10));
    };

    // post-barrier work for one row; n runtime (arithmetic only); s8, sl literal
    auto INGEST = [&](int n, int s8, int sl, float q0, float q1, float q2, float q3,
                      bool doEmit) {
        float4 hl = *(const float4*)&lrow[sl][c4];       // cols c4-4..c4-1
        float4 hr = *(const float4*)&lrow[sl][c4 + 8];   // cols c4+4..c4+7
        float l1 = hl.y, l2 = hl.z, l3 = hl.w;
        float r0 = hr.x, r1 = hr.y, r2 = hr.z;
        float a = ((l1 + l2) + (l3 + q0)) + ((q1 + q2) + q3);
        float b = a - l1 + r0;
        float c = b - l2 + r1;
        float d = c - l3 + r2;
        float4 old = rs_lds[(s8 + 1) & 7][tid];      // 7-ago window sums
        vs0 += a - old.x; vs1 += b - old.y; vs2 += c - old.z; vs3 += d - old.w;
        rs_lds[s8][tid] = make_float4(a, b, c, d);
        srm[s8] = l3; sr0[s8] = q0; sr1[s8] = q1; sr2[s8] = q2; sr3[s8] = q3; srp[s8] = r0;
        if (doEmit) {                                // emit row Y = band + n - 6
            const int Y = band + n - 6;
            float fy = (float)(7 - max(0, 3 - Y) - max(0, Y - (H - 4)));
            float wf0 = fy * wfxc0, wf1 = fy * wfxc1, wf2 = fy * wfxc2, wf3 = fy * wfxc3;
            const int sA = (s8 + 4) & 7, sB = (s8 + 5) & 7, sC = (s8 + 6) & 7;
            float A0 = srm[sA], A1 = sr0[sA], A2 = sr1[sA], A3 = sr2[sA], A4 = sr3[sA], A5 = srp[sA];
            float B0 = srm[sB], B1 = sr0[sB], B2 = sr1[sB], B3 = sr2[sB], B4 = sr3[sB], B5 = srp[sB];
            float C0 = srm[sC], C1 = sr0[sC], C2 = sr1[sC], C3 = sr2[sC], C4 = sr3[sC], C5 = srp[sC];
            float t0 = A0 + C0, t1 = A1 + C1, t2 = A2 + C2, t3 = A3 + C3, t4 = A4 + C4, t5 = A5 + C5;
            float u0 = A0 - C0, u1 = A1 - C1, u2 = A2 - C2, u3 = A3 - C3, u4 = A4 - C4, u5 = A5 - C5;
            auto PIXF = [&](float tp, float tp1, float tp2, float Bp, float Bp1, float Bp2,
                            float up, float up1, float up2, float vsv, float wf) {
                float sgx = (tp - tp2) + 2.f * (Bp - Bp2);
                float sgy = (up + up2) + 2.f * up1;
                float lp  = (Bp + Bp2) + tp1 - 4.f * Bp1;
                float edge = __builtin_amdgcn_sqrtf(sgx * sgx + sgy * sgy) + 0.5f * fabsf(lp);
                float dd = Bp1 - vsv * (1.f / 49.f);
                acc += ALPHA * edge + wf * (dd * dd);
            };
            PIXF(t0, t1, t2, B0, B1, B2, u0, u1, u2, vs0, wf0);
            PIXF(t1, t2, t3, B1, B2, B3, u1, u2, u3, vs1, wf1);
            PIXF(t2, t3, t4, B2, B3, B4, u2, u3, u4, vs2, wf2);
            PIXF(t3, t4, t5, B3, B4, B5, u3, u4, u5, vs3, wf3);
        }
    };

    // pair: ingest rows n, n+1 (global rows g, g+1); ONE barrier.
    // s8a/s8b (= n&7, (n+1)&7), sla/slb (= n&3, (n+1)&3), sva/svb literal.
    auto PAIR = [&](int n, int s8a, int s8b, int sla, int slb, int sva, int svb,
                    bool doEmit, bool doLoad) {
        const int g = band - 3 + n;
        float4 raw0 = vb[sva];
        float4 raw1 = vb[svb];
        if (doLoad) { LOADROW(g + 4, sva); LOADROW(g + 5, svb); }   // issue early
        float p0 = 0.f, p1 = 0.f, p2 = 0.f, p3 = 0.f;
        float q0 = 0.f, q1 = 0.f, q2 = 0.f, q3 = 0.f;
        if (g >= 0 && g < H) {
            p0 = sigf(raw0.x); p1 = sigf(raw0.y); p2 = sigf(raw0.z); p3 = sigf(raw0.w);
        }
        if (g + 1 >= 0 && g + 1 < H) {
            q0 = sigf(raw1.x); q1 = sigf(raw1.y); q2 = sigf(raw1.z); q3 = sigf(raw1.w);
        }
        *(float4*)&lrow[sla][c4 + 4] = make_float4(p0, p1, p2, p3);
        *(float4*)&lrow[slb][c4 + 4] = make_float4(q0, q1, q2, q3);
        block_sync_lds();
        INGEST(n,     s8a, sla, p0, p1, p2, p3, doEmit);
        INGEST(n + 1, s8b, slb, q0, q1, q2, q3, doEmit);
    };

    // ingest rows band-3 .. band+66 (70 rows = 35 pairs); emit band .. band+63
    LOADROW(band - 3, 0);
    LOADROW(band - 2, 1);
    LOADROW(band - 1, 2);
    LOADROW(band + 0, 3);
    PAIR(0, 0, 1, 0, 1, 0, 1, false, true);
    PAIR(2, 2, 3, 2, 3, 2, 3, false, true);
    PAIR(4, 4, 5, 0, 1, 0, 1, false, true);
    PAIR(6, 6, 7, 2, 3, 2, 3, true,  true);
    #pragma unroll 1
    for (int nn = 8; nn <= 56; nn += 8) {            // pairs 8..62; all slots literal
        PAIR(nn + 0, 0, 1, 0, 1, 0, 1, true, true);
        PAIR(nn + 2, 2, 3, 2, 3, 2, 3, true, true);
        PAIR(nn + 4, 4, 5, 0, 1, 0, 1, true, true);
        PAIR(nn + 6, 6, 7, 2, 3, 2, 3, true, true);
    }
    PAIR(64, 0, 1, 0, 1, 0, 1, true, true);          // loads band+65/66 for pair 68
    PAIR(66, 2, 3, 2, 3, 2, 3, true, false);
    PAIR(68, 4, 5, 0, 1, 0, 1, true, false);

    #pragma unroll
    for (int off = 32; off > 0; off >>= 1) acc += __shfl_down(acc, off);
    if (lane == 0) red[wvi] = acc;
    __syncthreads();
    if (tid == 0)
        scores_ws[ch * NBANDS + blockIdx.x] = red[0] + red[1] + red[2] + red[3];
}

// ---------------------------------------------------------------------------
// fuse_kernel v2: 2048 blocks x 8 float4/thread (24-deep load ILP vs v1's 12;
// v1 ran ~85us against a ~50us mixed L3/HBM floor -> latency-limited).
// Cacheable logits loads (L3-resident after score); nt stores.
// ---------------------------------------------------------------------------
__global__ __launch_bounds__(256)
void fuse_kernel(const float* __restrict__ logits,
                 const float* __restrict__ scores_ws,
                 const float* __restrict__ lw,
                 float* __restrict__ out) {
    const size_t HW4 = (size_t)(H * W) / 4;          // 2^18 float4 per plane

    const int b = blockIdx.x >> 7;                   // 2048 blocks, 128/image
    const float* sp = scores_ws + (size_t)b * 3 * NBANDS;
    float s0 = 0.f, s1 = 0.f, s2 = 0.f;
    #pragma unroll
    for (int i = 0; i < NBANDS; ++i) {
        s0 += sp[i];
        s1 += sp[NBANDS + i];
        s2 += sp[2 * NBANDS + i];
    }

    float l0 = lw[0], l1 = lw[1], l2 = lw[2];
    float mx = fmaxf(l0, fmaxf(l1, l2));
    float e0 = __expf(l0 - mx), e1 = __expf(l1 - mx), e2 = __expf(l2 - mx);
    float inv = __builtin_amdgcn_rcpf(e0 + e1 + e2);
    float itot = __builtin_amdgcn_rcpf(s0 + s1 + s2 + 1e-6f);
    float w0 = 0.5f * (s0 * itot + e0 * inv);
    float w1 = 0.5f * (s1 * itot + e1 * inv);
    float w2 = 0.5f * (s2 * itot + e2 * inv);

    size_t i0 = (size_t)blockIdx.x * 2048 + threadIdx.x;
    size_t r  = i0 & (HW4 - 1);
    const nfloat4* pb = (const nfloat4*)logits + (size_t)b * 3 * HW4 + r;
    nfloat4* po = (nfloat4*)out + i0;
    #pragma unroll
    for (int k = 0; k < 8; ++k) {
        nfloat4 x0 = pb[k * 256];
        nfloat4 x1 = pb[k * 256 + HW4];
        nfloat4 x2 = pb[k * 256 + 2 * HW4];
        nfloat4 o = x0 * w0 + x1 * w1 + x2 * w2;
        __builtin_nontemporal_store(o, po + k * 256);
    }
}

extern "C" void kernel_launch(void* const* d_in, const int* in_sizes, int n_in,
                              void* d_out, int out_size, void* d_ws, size_t ws_size,
                              hipStream_t stream) {
    const float* logits = (const float*)d_in[0];
    const float* lw     = (const float*)d_in[1];
    float* out       = (float*)d_out;
    float* scores_ws = (float*)d_ws;   // 48*16 floats, fully rewritten each run

    dim3 g1(NBANDS, NCH);              // (16, 48) = 768 blocks
    score_kernel<<<g1, 256, 0, stream>>>(logits, scores_ws);

    fuse_kernel<<<2048, 256, 0, stream>>>(logits, scores_ws, lw, out);
}